// Round 3
// baseline (123.792 us; speedup 1.0000x reference)
//
#include <hip/hip_runtime.h>
#include <hip/hip_bf16.h>
#include <hip/hip_cooperative_groups.h>

namespace cg = cooperative_groups;

// B=16384, C=32, S=12 symmetry-aware geodesic rotation loss.
// tr(R_pred @ (rot_s @ R_gt)^T) = <R_pred @ R_gt^T, rot_s>  (Frobenius dot)
// min_{s,c} theta == acos(clip(max_{s,c} tr))  (acos∘clip monotone non-incr).
// R3: single cooperative kernel — per-block partials, grid.sync(), block 0
// reduces. 1024 blocks x 256 thr = 4 blocks/CU needed; LDS 19.5 KB/block
// allows 8/CU, so co-residency holds with __launch_bounds__(256,4).

#define BPB 16          // batch elements per block
#define BLOCK 256
#define NB 16384
#define NC 32
#define NS 12
#define NBLK (NB / BPB) // 1024 blocks

__global__ __launch_bounds__(BLOCK, 4) void sym_loss_fused(
    const float* __restrict__ R_pred,   // (B, C, 3, 3)
    const float* __restrict__ R_gt,     // (B, 3, 3)
    const float* __restrict__ rot,      // (S, 3, 3)
    float* __restrict__ partial,        // (NBLK) in ws
    float* __restrict__ out)            // scalar
{
    __shared__ float s_rot[NS * 9];          // 108
    __shared__ float s_gt[BPB * 9];          // 144
    __shared__ float s_pred[BPB * NC * 9];   // 4608 floats = 18432 B
    __shared__ float s_theta[BPB];
    __shared__ float s_wave[4];

    const int tid = threadIdx.x;
    const int b0 = blockIdx.x * BPB;

    if (tid < NS * 9) s_rot[tid] = rot[tid];
    if (tid < BPB * 9) s_gt[tid] = R_gt[(size_t)b0 * 9 + tid];

    // Stage R_pred chunk (4608 floats, 16B-aligned) via coalesced float4.
    const float4* src = (const float4*)(R_pred + (size_t)b0 * NC * 9);
    float4* dst = (float4*)s_pred;
    #pragma unroll
    for (int i = tid; i < (BPB * NC * 9) / 4; i += BLOCK) dst[i] = src[i];
    __syncthreads();

    // 512 (b,c) pairs per block, 2 per thread.
    #pragma unroll
    for (int h = 0; h < 2; ++h) {
        const int p  = tid + h * BLOCK;        // pair index [0,512)
        const int lb = p >> 5;                 // local b [0,16)
        const float* P = &s_pred[p * 9];       // stride 9 (odd) -> conflict-free
        const float* G = &s_gt[lb * 9];        // broadcast across 32 lanes

        // M = R_pred @ R_gt^T
        float M[9];
        #pragma unroll
        for (int i = 0; i < 3; ++i)
            #pragma unroll
            for (int j = 0; j < 3; ++j)
                M[i * 3 + j] = fmaf(P[i * 3 + 0], G[j * 3 + 0],
                               fmaf(P[i * 3 + 1], G[j * 3 + 1],
                                    P[i * 3 + 2] * G[j * 3 + 2]));

        float mx = -1e30f;
        #pragma unroll
        for (int s = 0; s < NS; ++s) {
            const float* R = &s_rot[s * 9];    // broadcast
            float tr = 0.0f;
            #pragma unroll
            for (int e = 0; e < 9; ++e) tr = fmaf(M[e], R[e], tr);
            mx = fmaxf(mx, tr);
        }

        // max across the 32 lanes sharing this b (xor<32 stays in-half)
        #pragma unroll
        for (int m = 1; m < 32; m <<= 1) mx = fmaxf(mx, __shfl_xor(mx, m, 64));

        if ((p & 31) == 0) {
            const float lo = (float)(-1.0 + 1e-7);
            const float hi = (float)( 1.0 - 1e-7);
            float cosv = fminf(fmaxf((mx - 1.0f) * 0.5f, lo), hi);
            s_theta[lb] = acosf(cosv);
        }
    }
    __syncthreads();

    if (tid == 0) {
        float acc = 0.0f;
        #pragma unroll
        for (int i = 0; i < BPB; ++i) acc += s_theta[i];
        partial[blockIdx.x] = acc;             // plain store
    }

    cg::this_grid().sync();                    // includes memory visibility

    if (blockIdx.x == 0) {
        float acc = 0.0f;
        #pragma unroll
        for (int i = 0; i < NBLK / BLOCK; ++i) acc += partial[tid + i * BLOCK];

        #pragma unroll
        for (int m = 1; m < 64; m <<= 1) acc += __shfl_xor(acc, m, 64);

        if ((tid & 63) == 0) s_wave[tid >> 6] = acc;
        __syncthreads();

        if (tid == 0)
            *out = (s_wave[0] + s_wave[1] + s_wave[2] + s_wave[3]) * (1.0f / (float)NB);
    }
}

extern "C" void kernel_launch(void* const* d_in, const int* in_sizes, int n_in,
                              void* d_out, int out_size, void* d_ws, size_t ws_size,
                              hipStream_t stream) {
    const float* R_pred = (const float*)d_in[0];
    const float* R_gt   = (const float*)d_in[1];
    const float* rot    = (const float*)d_in[2];
    float* out = (float*)d_out;
    float* partial = (float*)d_ws;

    void* args[] = { (void*)&R_pred, (void*)&R_gt, (void*)&rot,
                     (void*)&partial, (void*)&out };
    hipLaunchCooperativeKernel((const void*)sym_loss_fused,
                               dim3(NBLK), dim3(BLOCK), args, 0, stream);
}

// Round 4
// 71.128 us; speedup vs baseline: 1.7404x; 1.7404x over previous
//
#include <hip/hip_runtime.h>
#include <hip/hip_bf16.h>

// B=16384, C=32, S=12 symmetry-aware geodesic rotation loss.
// tr(R_pred @ (rot_s @ R_gt)^T) = <R_pred @ R_gt^T, rot_s>  (Frobenius dot)
// min_{s,c} theta == acos(clip(max_{s,c} tr))  (acos∘clip monotone non-incr).
//
// R4: back to two plain kernels (R3's cooperative grid.sync cost ~50us —
// never again). BPB=16 -> 1024 blocks; reduce kernel reads partials as
// coalesced float4. No atomics, no memset, no init-value dependencies.

#define BPB 16          // batch elements per block
#define BLOCK 256
#define NB 16384
#define NC 32
#define NS 12
#define NBLK (NB / BPB) // 1024 blocks / partials

__global__ __launch_bounds__(BLOCK) void sym_loss_main(
    const float* __restrict__ R_pred,   // (B, C, 3, 3)
    const float* __restrict__ R_gt,     // (B, 3, 3)
    const float* __restrict__ rot,      // (S, 3, 3)
    float* __restrict__ partial)        // (NBLK)
{
    __shared__ float s_rot[NS * 9];          // 108
    __shared__ float s_gt[BPB * 9];          // 144
    __shared__ float s_pred[BPB * NC * 9];   // 4608 floats = 18432 B
    __shared__ float s_theta[BPB];

    const int tid = threadIdx.x;
    const int b0 = blockIdx.x * BPB;

    if (tid < NS * 9) s_rot[tid] = rot[tid];
    if (tid < BPB * 9) s_gt[tid] = R_gt[(size_t)b0 * 9 + tid];

    // Stage R_pred chunk (4608 floats, 16B-aligned) via coalesced float4.
    const float4* src = (const float4*)(R_pred + (size_t)b0 * NC * 9);
    float4* dst = (float4*)s_pred;
    #pragma unroll
    for (int i = tid; i < (BPB * NC * 9) / 4; i += BLOCK) dst[i] = src[i];
    __syncthreads();

    // 512 (b,c) pairs per block, 2 per thread.
    #pragma unroll
    for (int h = 0; h < 2; ++h) {
        const int p  = tid + h * BLOCK;        // pair index [0,512)
        const int lb = p >> 5;                 // local b [0,16)
        const float* P = &s_pred[p * 9];       // stride 9 (odd) -> conflict-free
        const float* G = &s_gt[lb * 9];        // broadcast across 32 lanes

        // M = R_pred @ R_gt^T
        float M[9];
        #pragma unroll
        for (int i = 0; i < 3; ++i)
            #pragma unroll
            for (int j = 0; j < 3; ++j)
                M[i * 3 + j] = fmaf(P[i * 3 + 0], G[j * 3 + 0],
                               fmaf(P[i * 3 + 1], G[j * 3 + 1],
                                    P[i * 3 + 2] * G[j * 3 + 2]));

        float mx = -1e30f;
        #pragma unroll
        for (int s = 0; s < NS; ++s) {
            const float* R = &s_rot[s * 9];    // broadcast
            float tr = 0.0f;
            #pragma unroll
            for (int e = 0; e < 9; ++e) tr = fmaf(M[e], R[e], tr);
            mx = fmaxf(mx, tr);
        }

        // max across the 32 lanes sharing this b (xor<32 stays in-half)
        #pragma unroll
        for (int m = 1; m < 32; m <<= 1) mx = fmaxf(mx, __shfl_xor(mx, m, 64));

        if ((p & 31) == 0) {
            const float lo = (float)(-1.0 + 1e-7);
            const float hi = (float)( 1.0 - 1e-7);
            float cosv = fminf(fmaxf((mx - 1.0f) * 0.5f, lo), hi);
            s_theta[lb] = acosf(cosv);
        }
    }
    __syncthreads();

    if (tid == 0) {
        float acc = 0.0f;
        #pragma unroll
        for (int i = 0; i < BPB; ++i) acc += s_theta[i];
        partial[blockIdx.x] = acc;             // plain store, no init needed
    }
}

__global__ __launch_bounds__(256) void sym_loss_reduce(
    const float* __restrict__ partial,  // (NBLK) contiguous
    float* __restrict__ out)            // scalar
{
    __shared__ float s_wave[4];
    const int tid = threadIdx.x;

    // 1024 floats = 256 lanes x float4, fully coalesced
    float4 v = ((const float4*)partial)[tid];
    float acc = (v.x + v.y) + (v.z + v.w);

    #pragma unroll
    for (int m = 1; m < 64; m <<= 1) acc += __shfl_xor(acc, m, 64);

    if ((tid & 63) == 0) s_wave[tid >> 6] = acc;
    __syncthreads();

    if (tid == 0)
        *out = (s_wave[0] + s_wave[1] + s_wave[2] + s_wave[3]) * (1.0f / (float)NB);
}

extern "C" void kernel_launch(void* const* d_in, const int* in_sizes, int n_in,
                              void* d_out, int out_size, void* d_ws, size_t ws_size,
                              hipStream_t stream) {
    const float* R_pred = (const float*)d_in[0];
    const float* R_gt   = (const float*)d_in[1];
    const float* rot    = (const float*)d_in[2];
    float* out = (float*)d_out;
    float* partial = (float*)d_ws;

    sym_loss_main<<<dim3(NBLK), dim3(BLOCK), 0, stream>>>(R_pred, R_gt, rot, partial);
    sym_loss_reduce<<<dim3(1), dim3(256), 0, stream>>>(partial, out);
}